// Round 1
// baseline (6123.935 us; speedup 1.0000x reference)
//
#include <hip/hip_runtime.h>
#include <hip/hip_bf16.h>
#include <math.h>

// Problem constants
#define BB 8
#define SS 512
#define DD 1024
#define LL 6
#define HH 8
#define HDD 128
#define FFF 4096
#define EPSF 1e-5f
#define SCALEF 0.08838834764831845f  // 1/sqrt(128)

typedef __attribute__((ext_vector_type(8))) _Float16 f16x8;
typedef __attribute__((ext_vector_type(4))) _Float16 f16x4;
typedef __attribute__((ext_vector_type(4))) float f32x4;

#define BM 128
#define BN 128
#define BKK 32
#define LDSLD 40  // BKK + 8 halves pad (80B rows: 16B aligned, bank-spread)

// ---------------------------------------------------------------------------
// GEMM: C = A[M,K] @ B[K,N] (TRANSB=0)  or  A[M,K] @ Bt[N,K]^T (TRANSB=1)
// fp32 in global, f16 staged in LDS, MFMA 16x16x32 f16, fp32 accum/out.
// emode: 0 plain(+bias) | 1 qkv-scatter(+bias) | 2 scores(scale+mask)
//        3 pv-scatter | 4 residual(+bias) | 5 gelu(+bias)
// ---------------------------------------------------------------------------
template <int TRANSB>
__global__ __launch_bounds__(256) void gemm_kernel(
    const float* __restrict__ Ag, const float* __restrict__ Bg,
    const float* __restrict__ bias, const float* __restrict__ res,
    float* __restrict__ outp, const int* __restrict__ amask,
    int Mdim, int Ndim, int Kdim,
    long zsA, long zsB, long zsOut, int emode) {
  __shared__ _Float16 lA[BM][LDSLD];
  __shared__ _Float16 lB[BN][LDSLD];

  const int tid = threadIdx.x;
  const int z = blockIdx.z;
  const int m0 = blockIdx.y * BM;
  const int n0 = blockIdx.x * BN;
  const float* Az = Ag + (long)z * zsA;
  const float* Bz = Bg + (long)z * zsB;

  const int lane = tid & 63;
  const int wid = tid >> 6;
  const int wm = (wid >> 1) * 64;
  const int wn = (wid & 1) * 64;
  const int r16 = lane & 15;
  const int koff = (lane >> 4) * 8;  // halves

  f32x4 acc[4][4];
#pragma unroll
  for (int mi = 0; mi < 4; ++mi)
#pragma unroll
    for (int ni = 0; ni < 4; ++ni) acc[mi][ni] = (f32x4){0.f, 0.f, 0.f, 0.f};

  for (int k0 = 0; k0 < Kdim; k0 += BKK) {
    __syncthreads();
// stage A tile [BM][BKK]: 128 rows x 32 cols fp32 -> f16
#pragma unroll
    for (int i = 0; i < 4; ++i) {
      int idx = tid + i * 256;
      int r = idx >> 3;
      int cq = (idx & 7) << 2;
      const float4 f =
          *reinterpret_cast<const float4*>(&Az[(long)(m0 + r) * Kdim + k0 + cq]);
      f16x4 hv = {(_Float16)f.x, (_Float16)f.y, (_Float16)f.z, (_Float16)f.w};
      *reinterpret_cast<f16x4*>(&lA[r][cq]) = hv;
    }
    if (TRANSB) {
// B given as Bt[N][K] row-major: lB[n][k] directly coalesced
#pragma unroll
      for (int i = 0; i < 4; ++i) {
        int idx = tid + i * 256;
        int r = idx >> 3;
        int cq = (idx & 7) << 2;
        const float4 f = *reinterpret_cast<const float4*>(
            &Bz[(long)(n0 + r) * Kdim + k0 + cq]);
        f16x4 hv = {(_Float16)f.x, (_Float16)f.y, (_Float16)f.z, (_Float16)f.w};
        *reinterpret_cast<f16x4*>(&lB[r][cq]) = hv;
      }
    } else {
// B given as B[K][N]: transpose into lB[n][k]
#pragma unroll
      for (int i = 0; i < 4; ++i) {
        int idx = tid + i * 256;
        int kk = idx >> 5;
        int nq = (idx & 31) << 2;
        const float4 f = *reinterpret_cast<const float4*>(
            &Bz[(long)(k0 + kk) * Ndim + n0 + nq]);
        lB[nq + 0][kk] = (_Float16)f.x;
        lB[nq + 1][kk] = (_Float16)f.y;
        lB[nq + 2][kk] = (_Float16)f.z;
        lB[nq + 3][kk] = (_Float16)f.w;
      }
    }
    __syncthreads();

    f16x8 af[4], bfr[4];
#pragma unroll
    for (int mi = 0; mi < 4; ++mi)
      af[mi] = *reinterpret_cast<const f16x8*>(&lA[wm + mi * 16 + r16][koff]);
#pragma unroll
    for (int ni = 0; ni < 4; ++ni)
      bfr[ni] = *reinterpret_cast<const f16x8*>(&lB[wn + ni * 16 + r16][koff]);
#pragma unroll
    for (int mi = 0; mi < 4; ++mi)
#pragma unroll
      for (int ni = 0; ni < 4; ++ni)
        acc[mi][ni] = __builtin_amdgcn_mfma_f32_16x16x32_f16(
            af[mi], bfr[ni], acc[mi][ni], 0, 0, 0);
  }

  float* outz = outp + (long)z * zsOut;
#pragma unroll
  for (int mi = 0; mi < 4; ++mi) {
#pragma unroll
    for (int ni = 0; ni < 4; ++ni) {
      const int col = n0 + wn + ni * 16 + r16;
#pragma unroll
      for (int j = 0; j < 4; ++j) {
        const int row = m0 + wm + mi * 16 + ((lane >> 4) << 2) + j;
        float vv = acc[mi][ni][j];
        if (emode == 0) {
          if (bias) vv += bias[col];
          outz[(long)row * Ndim + col] = vv;
        } else if (emode == 1) {  // qkv scatter: [B,S,D] row -> [B,H,S,HD]
          vv += bias[col];
          int b_ = row >> 9, s_ = row & 511;
          int hh = col >> 7, hd_ = col & 127;
          outz[(((long)(b_ * HH + hh)) * SS + s_) * HDD + hd_] = vv;
        } else if (emode == 2) {  // scores: scale + key-pad mask
          int b_ = z >> 3;
          vv = (amask[b_ * SS + col] == 0) ? -10000.0f : vv * SCALEF;
          outz[(long)row * Ndim + col] = vv;
        } else if (emode == 3) {  // pv scatter: per-(b,h) [S,HD] -> [B,S,D]
          int b_ = z >> 3, hh = z & 7;
          outz[((long)(b_ * SS + row)) * DD + hh * HDD + col] = vv;
        } else if (emode == 4) {  // residual + bias
          vv += bias[col] + res[(long)row * Ndim + col];
          outz[(long)row * Ndim + col] = vv;
        } else {  // 5: exact GELU(bias+acc)
          vv += bias[col];
          vv = 0.5f * vv * (1.0f + erff(vv * 0.70710678118654752f));
          outz[(long)row * Ndim + col] = vv;
        }
      }
    }
  }
}

// ---------------------------------------------------------------------------
__global__ __launch_bounds__(256) void embed_kernel(
    const int* __restrict__ ids, const int* __restrict__ curpos,
    const float* __restrict__ tok, const float* __restrict__ pos,
    float* __restrict__ h) {
  const int rs = blockIdx.x;  // b*S+s
  const int s_ = rs & (SS - 1);
  const int t = ids[rs];
  const int p = curpos[0] + s_;
  const int c = threadIdx.x << 2;
  const float4 tv = *reinterpret_cast<const float4*>(&tok[(long)t * DD + c]);
  const float4 pv = *reinterpret_cast<const float4*>(&pos[(long)p * DD + c]);
  float4 o = {tv.x + pv.x, tv.y + pv.y, tv.z + pv.z, tv.w + pv.w};
  *reinterpret_cast<float4*>(&h[(long)rs * DD + c]) = o;
}

__global__ __launch_bounds__(256) void ln_kernel(const float* __restrict__ in,
                                                 const float* __restrict__ g,
                                                 const float* __restrict__ bb,
                                                 float* __restrict__ out) {
  const int row = blockIdx.x;
  const int c = threadIdx.x << 2;
  const float4 xv = *reinterpret_cast<const float4*>(&in[(long)row * DD + c]);
  float s = xv.x + xv.y + xv.z + xv.w;
  float ss = xv.x * xv.x + xv.y * xv.y + xv.z * xv.z + xv.w * xv.w;
#pragma unroll
  for (int off = 32; off; off >>= 1) {
    s += __shfl_down(s, off);
    ss += __shfl_down(ss, off);
  }
  __shared__ float red[8];
  const int wid = threadIdx.x >> 6, lane = threadIdx.x & 63;
  if (lane == 0) {
    red[wid] = s;
    red[4 + wid] = ss;
  }
  __syncthreads();
  if (threadIdx.x == 0) {
    s = red[0] + red[1] + red[2] + red[3];
    ss = red[4] + red[5] + red[6] + red[7];
    float mean = s * (1.0f / DD);
    float var = ss * (1.0f / DD) - mean * mean;
    red[0] = mean;
    red[1] = rsqrtf(var + EPSF);
  }
  __syncthreads();
  const float mean = red[0], rstd = red[1];
  const float4 gv = *reinterpret_cast<const float4*>(&g[c]);
  const float4 bv = *reinterpret_cast<const float4*>(&bb[c]);
  float4 o;
  o.x = (xv.x - mean) * rstd * gv.x + bv.x;
  o.y = (xv.y - mean) * rstd * gv.y + bv.y;
  o.z = (xv.z - mean) * rstd * gv.z + bv.z;
  o.w = (xv.w - mean) * rstd * gv.w + bv.w;
  *reinterpret_cast<float4*>(&out[(long)row * DD + c]) = o;
}

// wave-per-row softmax over 512 cols (scale+mask already applied)
__global__ __launch_bounds__(256) void softmax_kernel(float* __restrict__ p) {
  const long row = (long)blockIdx.x * 4 + (threadIdx.x >> 6);
  const int lane = threadIdx.x & 63;
  float* pr = p + row * SS;
  float4 a = *reinterpret_cast<const float4*>(&pr[lane * 8]);
  float4 b = *reinterpret_cast<const float4*>(&pr[lane * 8 + 4]);
  float m = fmaxf(fmaxf(fmaxf(a.x, a.y), fmaxf(a.z, a.w)),
                  fmaxf(fmaxf(b.x, b.y), fmaxf(b.z, b.w)));
#pragma unroll
  for (int off = 1; off < 64; off <<= 1) m = fmaxf(m, __shfl_xor(m, off));
  a.x = expf(a.x - m);
  a.y = expf(a.y - m);
  a.z = expf(a.z - m);
  a.w = expf(a.w - m);
  b.x = expf(b.x - m);
  b.y = expf(b.y - m);
  b.z = expf(b.z - m);
  b.w = expf(b.w - m);
  float sum = a.x + a.y + a.z + a.w + b.x + b.y + b.z + b.w;
#pragma unroll
  for (int off = 1; off < 64; off <<= 1) sum += __shfl_xor(sum, off);
  const float inv = 1.0f / sum;
  a.x *= inv;
  a.y *= inv;
  a.z *= inv;
  a.w *= inv;
  b.x *= inv;
  b.y *= inv;
  b.z *= inv;
  b.w *= inv;
  *reinterpret_cast<float4*>(&pr[lane * 8]) = a;
  *reinterpret_cast<float4*>(&pr[lane * 8 + 4]) = b;
}

// ---------------------------------------------------------------------------
extern "C" void kernel_launch(void* const* d_in, const int* in_sizes, int n_in,
                              void* d_out, int out_size, void* d_ws,
                              size_t ws_size, hipStream_t stream) {
  const int* ids = (const int*)d_in[0];
  const int* amask = (const int*)d_in[1];
  const int* curp = (const int*)d_in[2];
  const float* tok = (const float*)d_in[3];
  const float* pose = (const float*)d_in[4];
  const float* ln1s = (const float*)d_in[5];
  const float* ln1b = (const float*)d_in[6];
  const float* Wq = (const float*)d_in[7];
  const float* bq = (const float*)d_in[8];
  const float* Wk = (const float*)d_in[9];
  const float* bk = (const float*)d_in[10];
  const float* Wv = (const float*)d_in[11];
  const float* bv = (const float*)d_in[12];
  const float* Wo = (const float*)d_in[13];
  const float* bo = (const float*)d_in[14];
  const float* ln2s = (const float*)d_in[15];
  const float* ln2b = (const float*)d_in[16];
  const float* W1 = (const float*)d_in[17];
  const float* b1 = (const float*)d_in[18];
  const float* W2 = (const float*)d_in[19];
  const float* b2 = (const float*)d_in[20];
  const float* lnfs = (const float*)d_in[21];
  const float* lnfb = (const float*)d_in[22];
  const float* Wout = (const float*)d_in[23];
  const float* bout = (const float*)d_in[24];

  const long MSZ = (long)BB * SS * DD;  // 4,194,304 floats
  float* h = (float*)d_ws;
  float* x = h + MSZ;
  float* q = x + MSZ;
  float* k = q + MSZ;
  float* v = k + MSZ;
  float* big = v + MSZ;  // B*H*S*S = 16,777,216 floats (scores / MLP mid)

  const int M = BB * SS;  // 4096
  dim3 blk(256);

  embed_kernel<<<M, blk, 0, stream>>>(ids, curp, tok, pose, h);

  const dim3 gP(DD / BN, M / BM, 1);    // 8,32   proj GEMMs
  const dim3 gS(SS / BN, SS / BM, BB * HH);  // 4,4,64 scores
  const dim3 gV(HDD / BN, SS / BM, BB * HH); // 1,4,64 PV
  const dim3 gF1(FFF / BN, M / BM, 1);  // 32,32  MLP up

  for (int l = 0; l < LL; ++l) {
    const float* wq = Wq + (long)l * DD * DD;
    const float* wk = Wk + (long)l * DD * DD;
    const float* wv = Wv + (long)l * DD * DD;
    const float* wo = Wo + (long)l * DD * DD;
    const float* w1 = W1 + (long)l * DD * FFF;
    const float* w2 = W2 + (long)l * FFF * DD;

    ln_kernel<<<M, blk, 0, stream>>>(h, ln1s + l * DD, ln1b + l * DD, x);
    gemm_kernel<0><<<gP, blk, 0, stream>>>(x, wq, bq + l * DD, nullptr, q,
                                           nullptr, M, DD, DD, 0, 0, 0, 1);
    gemm_kernel<0><<<gP, blk, 0, stream>>>(x, wk, bk + l * DD, nullptr, k,
                                           nullptr, M, DD, DD, 0, 0, 0, 1);
    gemm_kernel<0><<<gP, blk, 0, stream>>>(x, wv, bv + l * DD, nullptr, v,
                                           nullptr, M, DD, DD, 0, 0, 0, 1);
    gemm_kernel<1><<<gS, blk, 0, stream>>>(
        q, k, nullptr, nullptr, big, amask, SS, SS, HDD, (long)SS * HDD,
        (long)SS * HDD, (long)SS * SS, 2);
    softmax_kernel<<<(BB * HH * SS) / 4, blk, 0, stream>>>(big);
    gemm_kernel<0><<<gV, blk, 0, stream>>>(
        big, v, nullptr, nullptr, x, nullptr, SS, HDD, SS, (long)SS * SS,
        (long)SS * HDD, 0, 3);
    gemm_kernel<0><<<gP, blk, 0, stream>>>(x, wo, bo + l * DD, h, h, nullptr,
                                           M, DD, DD, 0, 0, 0, 4);
    ln_kernel<<<M, blk, 0, stream>>>(h, ln2s + l * DD, ln2b + l * DD, x);
    gemm_kernel<0><<<gF1, blk, 0, stream>>>(x, w1, b1 + l * FFF, nullptr, big,
                                            nullptr, M, FFF, DD, 0, 0, 0, 5);
    gemm_kernel<0><<<gP, blk, 0, stream>>>(big, w2, b2 + l * DD, h, h, nullptr,
                                           M, DD, FFF, 0, 0, 0, 4);
  }
  ln_kernel<<<M, blk, 0, stream>>>(h, lnfs, lnfb, x);
  gemm_kernel<0><<<gP, blk, 0, stream>>>(x, Wout, bout, nullptr, (float*)d_out,
                                         nullptr, M, DD, DD, 0, 0, 0, 0);
}

// Round 2
// 2591.713 us; speedup vs baseline: 2.3629x; 2.3629x over previous
//
#include <hip/hip_runtime.h>
#include <hip/hip_bf16.h>
#include <math.h>

#define BB 8
#define SS 512
#define DD 1024
#define LL 6
#define HH 8
#define HDD 128
#define FFF 4096
#define EPSF 1e-5f
#define SCALEF 0.08838834764831845f  // 1/sqrt(128)

typedef __attribute__((ext_vector_type(8))) _Float16 f16x8;
typedef __attribute__((ext_vector_type(4))) _Float16 f16x4;
typedef __attribute__((ext_vector_type(4))) float f32x4;

__device__ __forceinline__ void gload16(const void* g, void* l) {
  __builtin_amdgcn_global_load_lds(
      (const __attribute__((address_space(1))) void*)g,
      (__attribute__((address_space(3))) void*)l, 16, 0, 0);
}

// ---------------------------------------------------------------------------
// f16 GEMM, m97 structure: 128x128 tile, BK=64, 4 waves 2x2, 16x16x32 MFMA,
// global_load_lds w16 staging, XOR-swizzle (row&7)<<4 both-sides.
// A [M,K] f16 row-major; B [N,K] f16 row-major (pre-transposed weights).
// emode: 0 f32+bias | 1 f16 qkv-scatter+bias | 2 f16 scores(scale+mask)
//        3 f16 pv-scatter | 4 f32 residual+bias | 5 f16 gelu+bias
// ---------------------------------------------------------------------------
__global__ __launch_bounds__(256) void gemm2_kernel(
    const _Float16* __restrict__ Ag, const _Float16* __restrict__ Bg,
    const float* __restrict__ bias, const float* __restrict__ res,
    void* __restrict__ outp, const int* __restrict__ amask,
    int Mdim, int Ndim, int Kdim, long zsA, long zsB, long zsOut, int emode) {
  __shared__ _Float16 lA[128 * 64];
  __shared__ _Float16 lB[128 * 64];
  const int tid = threadIdx.x;
  const int lane = tid & 63;
  const int wid = tid >> 6;
  const int z = blockIdx.z;
  const int m0 = blockIdx.y * 128;
  const int n0 = blockIdx.x * 128;
  const _Float16* Az = Ag + (long)z * zsA + (long)m0 * Kdim;
  const _Float16* Bz = Bg + (long)z * zsB + (long)n0 * Kdim;

  const int wm = (wid >> 1) * 64;
  const int wn = (wid & 1) * 64;
  const int r16 = lane & 15;
  const int kq = (lane >> 4) * 16;  // byte offset of this lane's k-quarter

  f32x4 acc[4][4];
#pragma unroll
  for (int mi = 0; mi < 4; ++mi)
#pragma unroll
    for (int ni = 0; ni < 4; ++ni) acc[mi][ni] = (f32x4){0.f, 0.f, 0.f, 0.f};

  // staging geometry: load i stages LDS bytes [(i*4+wid)*1024, +1024), lane*16
  int sr[4], sc[4];
#pragma unroll
  for (int i = 0; i < 4; ++i) {
    int o = ((i * 4 + wid) * 64 + lane) * 16;  // linear byte offset in tile
    int r = o >> 7;                            // row (64 halves = 128B)
    sr[i] = r;
    sc[i] = (o & 127) ^ ((r & 7) << 4);        // swizzled source column-byte
  }

  for (int k0 = 0; k0 < Kdim; k0 += 64) {
    __syncthreads();
#pragma unroll
    for (int i = 0; i < 4; ++i) {
      gload16((const char*)(Az + (long)sr[i] * Kdim + k0) + sc[i],
              (char*)lA + (i * 4 + wid) * 1024);
      gload16((const char*)(Bz + (long)sr[i] * Kdim + k0) + sc[i],
              (char*)lB + (i * 4 + wid) * 1024);
    }
    __syncthreads();
#pragma unroll
    for (int kk = 0; kk < 2; ++kk) {
      f16x8 af[4], bf[4];
#pragma unroll
      for (int mi = 0; mi < 4; ++mi) {
        const int R = wm + mi * 16 + r16;
        af[mi] = *(const f16x8*)((const char*)lA + R * 128 +
                                 ((kk * 64 + kq) ^ ((R & 7) << 4)));
      }
#pragma unroll
      for (int ni = 0; ni < 4; ++ni) {
        const int R = wn + ni * 16 + r16;
        bf[ni] = *(const f16x8*)((const char*)lB + R * 128 +
                                 ((kk * 64 + kq) ^ ((R & 7) << 4)));
      }
#pragma unroll
      for (int mi = 0; mi < 4; ++mi)
#pragma unroll
        for (int ni = 0; ni < 4; ++ni)
          acc[mi][ni] = __builtin_amdgcn_mfma_f32_16x16x32_f16(
              af[mi], bf[ni], acc[mi][ni], 0, 0, 0);
    }
  }

  float* outF = (float*)outp + (long)z * zsOut;
  _Float16* outH = (_Float16*)outp + (long)z * zsOut;
  const int rj = (lane >> 4) << 2;
#pragma unroll
  for (int mi = 0; mi < 4; ++mi) {
#pragma unroll
    for (int ni = 0; ni < 4; ++ni) {
      const int col = n0 + wn + ni * 16 + r16;
#pragma unroll
      for (int j = 0; j < 4; ++j) {
        const int row = m0 + wm + mi * 16 + rj + j;
        float vv = acc[mi][ni][j];
        if (emode == 0) {
          if (bias) vv += bias[col];
          outF[(long)row * Ndim + col] = vv;
        } else if (emode == 1) {  // qkv scatter [B,S,D]-row -> [B,H,S,HD] f16
          vv += bias[col];
          int b_ = row >> 9, s_ = row & 511;
          int hh = col >> 7, hd_ = col & 127;
          outH[(((long)(b_ * HH + hh)) * SS + s_) * HDD + hd_] = (_Float16)vv;
        } else if (emode == 2) {  // scores: scale + key-pad mask, f16
          int b_ = z >> 3;
          vv = (amask[b_ * SS + col] == 0) ? -10000.0f : vv * SCALEF;
          outH[(long)row * Ndim + col] = (_Float16)vv;
        } else if (emode == 3) {  // pv scatter -> x [B,S,D] f16
          int b_ = z >> 3, hh = z & 7;
          outH[((long)(b_ * SS + row)) * DD + hh * HDD + col] = (_Float16)vv;
        } else if (emode == 4) {  // residual + bias, f32
          vv += bias[col] + res[(long)row * Ndim + col];
          outF[(long)row * Ndim + col] = vv;
        } else {  // 5: exact GELU(bias+acc), f16
          vv += bias[col];
          vv = 0.5f * vv * (1.0f + erff(vv * 0.70710678118654752f));
          outH[(long)row * Ndim + col] = (_Float16)vv;
        }
      }
    }
  }
}

// ---------------------------------------------------------------------------
__global__ __launch_bounds__(256) void embed_kernel(
    const int* __restrict__ ids, const int* __restrict__ curpos,
    const float* __restrict__ tok, const float* __restrict__ pos,
    float* __restrict__ h) {
  const int rs = blockIdx.x;
  const int s_ = rs & (SS - 1);
  const int t = ids[rs];
  const int p = curpos[0] + s_;
  const int c = threadIdx.x << 2;
  const float4 tv = *reinterpret_cast<const float4*>(&tok[(long)t * DD + c]);
  const float4 pv = *reinterpret_cast<const float4*>(&pos[(long)p * DD + c]);
  float4 o = {tv.x + pv.x, tv.y + pv.y, tv.z + pv.z, tv.w + pv.w};
  *reinterpret_cast<float4*>(&h[(long)rs * DD + c]) = o;
}

// LN: f32 in -> f16 out
__global__ __launch_bounds__(256) void ln_kernel(const float* __restrict__ in,
                                                 const float* __restrict__ g,
                                                 const float* __restrict__ bb,
                                                 _Float16* __restrict__ out) {
  const int row = blockIdx.x;
  const int c = threadIdx.x << 2;
  const float4 xv = *reinterpret_cast<const float4*>(&in[(long)row * DD + c]);
  float s = xv.x + xv.y + xv.z + xv.w;
  float ss = xv.x * xv.x + xv.y * xv.y + xv.z * xv.z + xv.w * xv.w;
#pragma unroll
  for (int off = 32; off; off >>= 1) {
    s += __shfl_down(s, off);
    ss += __shfl_down(ss, off);
  }
  __shared__ float red[8];
  const int wid = threadIdx.x >> 6, lane = threadIdx.x & 63;
  if (lane == 0) {
    red[wid] = s;
    red[4 + wid] = ss;
  }
  __syncthreads();
  if (threadIdx.x == 0) {
    s = red[0] + red[1] + red[2] + red[3];
    ss = red[4] + red[5] + red[6] + red[7];
    float mean = s * (1.0f / DD);
    float var = ss * (1.0f / DD) - mean * mean;
    red[0] = mean;
    red[1] = rsqrtf(var + EPSF);
  }
  __syncthreads();
  const float mean = red[0], rstd = red[1];
  const float4 gv = *reinterpret_cast<const float4*>(&g[c]);
  const float4 bv = *reinterpret_cast<const float4*>(&bb[c]);
  f16x4 o;
  o[0] = (_Float16)((xv.x - mean) * rstd * gv.x + bv.x);
  o[1] = (_Float16)((xv.y - mean) * rstd * gv.y + bv.y);
  o[2] = (_Float16)((xv.z - mean) * rstd * gv.z + bv.z);
  o[3] = (_Float16)((xv.w - mean) * rstd * gv.w + bv.w);
  *reinterpret_cast<f16x4*>(&out[(long)row * DD + c]) = o;
}

// wave-per-row softmax over 512 f16 cols, in place
__global__ __launch_bounds__(256) void softmax_kernel(_Float16* __restrict__ p) {
  const long row = (long)blockIdx.x * 4 + (threadIdx.x >> 6);
  const int lane = threadIdx.x & 63;
  _Float16* pr = p + row * SS;
  f16x8 hv = *reinterpret_cast<const f16x8*>(&pr[lane * 8]);
  float v[8];
#pragma unroll
  for (int j = 0; j < 8; ++j) v[j] = (float)hv[j];
  float m = v[0];
#pragma unroll
  for (int j = 1; j < 8; ++j) m = fmaxf(m, v[j]);
#pragma unroll
  for (int off = 1; off < 64; off <<= 1) m = fmaxf(m, __shfl_xor(m, off));
  float sum = 0.f;
#pragma unroll
  for (int j = 0; j < 8; ++j) {
    v[j] = expf(v[j] - m);
    sum += v[j];
  }
#pragma unroll
  for (int off = 1; off < 64; off <<= 1) sum += __shfl_xor(sum, off);
  const float inv = 1.0f / sum;
#pragma unroll
  for (int j = 0; j < 8; ++j) hv[j] = (_Float16)(v[j] * inv);
  *reinterpret_cast<f16x8*>(&pr[lane * 8]) = hv;
}

// W [K][N] f32 -> WT [N][K] f16  (64x64 tiles via LDS)
__global__ __launch_bounds__(256) void wtrans_kernel(
    const float* __restrict__ W, _Float16* __restrict__ WT, int K, int N) {
  __shared__ float t[64][65];
  const int n0 = blockIdx.x * 64, k0 = blockIdx.y * 64;
  const int tx = threadIdx.x & 63;
  const int ty = threadIdx.x >> 6;
#pragma unroll
  for (int i = 0; i < 16; ++i)
    t[i * 4 + ty][tx] = W[(long)(k0 + i * 4 + ty) * N + n0 + tx];
  __syncthreads();
#pragma unroll
  for (int i = 0; i < 16; ++i) {
    const int r = i * 4 + ty;
    WT[(long)(n0 + r) * K + k0 + tx] = (_Float16)t[tx][r];
  }
}

// V [z][S][HD] f16 -> VT [z][HD][S] f16
__global__ __launch_bounds__(256) void vtrans_kernel(
    const _Float16* __restrict__ V, _Float16* __restrict__ VT) {
  __shared__ _Float16 t[64][66];
  const int z = blockIdx.z;
  const int hd0 = blockIdx.x * 64, s0 = blockIdx.y * 64;
  const int tx = threadIdx.x & 63;
  const int ty = threadIdx.x >> 6;
  const _Float16* Vz = V + (long)z * SS * HDD;
  _Float16* VTz = VT + (long)z * SS * HDD;
#pragma unroll
  for (int i = 0; i < 16; ++i)
    t[i * 4 + ty][tx] = Vz[(long)(s0 + i * 4 + ty) * HDD + hd0 + tx];
  __syncthreads();
#pragma unroll
  for (int i = 0; i < 16; ++i) {
    const int r = i * 4 + ty;
    VTz[(long)(hd0 + r) * SS + s0 + tx] = t[tx][r];
  }
}

// ---------------------------------------------------------------------------
extern "C" void kernel_launch(void* const* d_in, const int* in_sizes, int n_in,
                              void* d_out, int out_size, void* d_ws,
                              size_t ws_size, hipStream_t stream) {
  const int* ids = (const int*)d_in[0];
  const int* amask = (const int*)d_in[1];
  const int* curp = (const int*)d_in[2];
  const float* tok = (const float*)d_in[3];
  const float* pose = (const float*)d_in[4];
  const float* ln1s = (const float*)d_in[5];
  const float* ln1b = (const float*)d_in[6];
  const float* Wq = (const float*)d_in[7];
  const float* bq = (const float*)d_in[8];
  const float* Wk = (const float*)d_in[9];
  const float* bk = (const float*)d_in[10];
  const float* Wv = (const float*)d_in[11];
  const float* bv = (const float*)d_in[12];
  const float* Wo = (const float*)d_in[13];
  const float* bo = (const float*)d_in[14];
  const float* ln2s = (const float*)d_in[15];
  const float* ln2b = (const float*)d_in[16];
  const float* W1 = (const float*)d_in[17];
  const float* b1 = (const float*)d_in[18];
  const float* W2 = (const float*)d_in[19];
  const float* b2 = (const float*)d_in[20];
  const float* lnfs = (const float*)d_in[21];
  const float* lnfb = (const float*)d_in[22];
  const float* Wout = (const float*)d_in[23];
  const float* bout = (const float*)d_in[24];

  const long MSZ = (long)BB * SS * DD;  // 4M elements
  char* wsp = (char*)d_ws;
  float* h = (float*)wsp;                      // 16MB f32
  _Float16* x = (_Float16*)(wsp + 16u * 1024 * 1024);   // 8MB
  _Float16* q = x + MSZ;                        // 8MB
  _Float16* kb = q + MSZ;                       // 8MB
  _Float16* vb = kb + MSZ;                      // 8MB
  _Float16* vt = vb + MSZ;                      // 8MB
  _Float16* big = vt + MSZ;                     // 32MB (scores/probs, MLP mid)
  _Float16* wqT = big + (long)BB * HH * SS * SS;  // 2MB each
  _Float16* wkT = wqT + (long)DD * DD;
  _Float16* wvT = wkT + (long)DD * DD;
  _Float16* woT = wvT + (long)DD * DD;
  _Float16* w1T = woT + (long)DD * DD;          // 8MB
  _Float16* w2T = w1T + (long)DD * FFF;         // 8MB

  const int M = BB * SS;  // 4096
  dim3 blk(256);

  embed_kernel<<<M, blk, 0, stream>>>(ids, curp, tok, pose, h);

  const dim3 gP(DD / 128, M / 128, 1);        // proj GEMMs (8,32)
  const dim3 gS(SS / 128, SS / 128, BB * HH); // scores (4,4,64)
  const dim3 gV(HDD / 128, SS / 128, BB * HH);// pv (1,4,64)
  const dim3 gF1(FFF / 128, M / 128, 1);      // mlp up (32,32)
  const dim3 gWt(DD / 64, DD / 64);           // DxD weight transpose
  const dim3 gW1t(FFF / 64, DD / 64);
  const dim3 gW2t(DD / 64, FFF / 64);
  const dim3 gVt(HDD / 64, SS / 64, BB * HH);

  for (int l = 0; l < LL; ++l) {
    wtrans_kernel<<<gWt, blk, 0, stream>>>(Wq + (long)l * DD * DD, wqT, DD, DD);
    wtrans_kernel<<<gWt, blk, 0, stream>>>(Wk + (long)l * DD * DD, wkT, DD, DD);
    wtrans_kernel<<<gWt, blk, 0, stream>>>(Wv + (long)l * DD * DD, wvT, DD, DD);
    wtrans_kernel<<<gWt, blk, 0, stream>>>(Wo + (long)l * DD * DD, woT, DD, DD);
    wtrans_kernel<<<gW1t, blk, 0, stream>>>(W1 + (long)l * DD * FFF, w1T, DD, FFF);
    wtrans_kernel<<<gW2t, blk, 0, stream>>>(W2 + (long)l * FFF * DD, w2T, FFF, DD);

    ln_kernel<<<M, blk, 0, stream>>>(h, ln1s + l * DD, ln1b + l * DD, x);
    gemm2_kernel<<<gP, blk, 0, stream>>>(x, wqT, bq + l * DD, nullptr, q,
                                         nullptr, M, DD, DD, 0, 0, 0, 1);
    gemm2_kernel<<<gP, blk, 0, stream>>>(x, wkT, bk + l * DD, nullptr, kb,
                                         nullptr, M, DD, DD, 0, 0, 0, 1);
    gemm2_kernel<<<gP, blk, 0, stream>>>(x, wvT, bv + l * DD, nullptr, vb,
                                         nullptr, M, DD, DD, 0, 0, 0, 1);
    vtrans_kernel<<<gVt, blk, 0, stream>>>(vb, vt);
    gemm2_kernel<<<gS, blk, 0, stream>>>(q, kb, nullptr, nullptr, big, amask,
                                         SS, SS, HDD, (long)SS * HDD,
                                         (long)SS * HDD, (long)SS * SS, 2);
    softmax_kernel<<<(BB * HH * SS) / 4, blk, 0, stream>>>(big);
    gemm2_kernel<<<gV, blk, 0, stream>>>(big, vt, nullptr, nullptr, x, nullptr,
                                         SS, HDD, SS, (long)SS * SS,
                                         (long)SS * HDD, 0, 3);
    gemm2_kernel<<<gP, blk, 0, stream>>>(x, woT, bo + l * DD, h, h, nullptr, M,
                                         DD, DD, 0, 0, 0, 4);
    ln_kernel<<<M, blk, 0, stream>>>(h, ln2s + l * DD, ln2b + l * DD, x);
    gemm2_kernel<<<gF1, blk, 0, stream>>>(x, w1T, b1 + l * FFF, nullptr, big,
                                          nullptr, M, FFF, DD, 0, 0, 0, 5);
    gemm2_kernel<<<gP, blk, 0, stream>>>(big, w2T, b2 + l * DD, h, h, nullptr,
                                         M, DD, FFF, 0, 0, 0, 4);
  }
  ln_kernel<<<M, blk, 0, stream>>>(h, lnfs, lnfb, x);
  wtrans_kernel<<<gWt, blk, 0, stream>>>(Wout, wqT, DD, DD);
  gemm2_kernel<<<gP, blk, 0, stream>>>(x, wqT, bout, nullptr, (float*)d_out,
                                       nullptr, M, DD, DD, 0, 0, 0, 0);
}

// Round 3
// 2295.811 us; speedup vs baseline: 2.6674x; 1.1289x over previous
//
#include <hip/hip_runtime.h>
#include <hip/hip_bf16.h>
#include <math.h>

#define BB 8
#define SS 512
#define DD 1024
#define LL 6
#define HH 8
#define HDD 128
#define FFF 4096
#define EPSF 1e-5f
#define SCALEF 0.08838834764831845f  // 1/sqrt(128)

typedef __attribute__((ext_vector_type(8))) _Float16 f16x8;
typedef __attribute__((ext_vector_type(4))) _Float16 f16x4;
typedef __attribute__((ext_vector_type(4))) float f32x4;

__device__ __forceinline__ void gload16(const void* g, void* l) {
  __builtin_amdgcn_global_load_lds(
      (const __attribute__((address_space(1))) void*)g,
      (__attribute__((address_space(3))) void*)l, 16, 0, 0);
}

// ---------------------------------------------------------------------------
// f16 GEMM: 128x128 tile, BK=64, 4 waves 2x2, 16x16x32 MFMA,
// global_load_lds w16, XOR-swizzle (row&7)<<4 both-sides,
// 2-phase double-buffered pipeline (stage t+1 issued before compute t,
// single barrier per K-step).
// A [M,K] f16 row-major; B [N,K] f16 row-major.
// emode: 0 f32+bias | 1 fused-qkv scatter (N=3072, V transposed) |
//        2 f16 scores(scale+mask) | 3 f16 pv-scatter | 4 f32 residual+bias |
//        5 f16 gelu+bias
// ---------------------------------------------------------------------------
#define STAGE_TILE(LA, LB, K0)                                              \
  {                                                                         \
    _Pragma("unroll") for (int i = 0; i < 4; ++i) {                         \
      gload16((const char*)(Az + (long)sr[i] * Kdim + (K0)) + sc[i],        \
              (char*)(LA) + (i * 4 + wid) * 1024);                          \
      gload16((const char*)(Bz + (long)sr[i] * Kdim + (K0)) + sc[i],        \
              (char*)(LB) + (i * 4 + wid) * 1024);                          \
    }                                                                       \
  }

#define COMPUTE_TILE(LA, LB)                                                \
  {                                                                         \
    _Pragma("unroll") for (int kk = 0; kk < 2; ++kk) {                      \
      f16x8 af[4], bf[4];                                                   \
      _Pragma("unroll") for (int mi = 0; mi < 4; ++mi) {                    \
        const int R = wm + mi * 16 + r16;                                   \
        af[mi] = *(const f16x8*)((const char*)(LA) + R * 128 +              \
                                 ((kk * 64 + kq) ^ ((R & 7) << 4)));        \
      }                                                                     \
      _Pragma("unroll") for (int ni = 0; ni < 4; ++ni) {                    \
        const int R = wn + ni * 16 + r16;                                   \
        bf[ni] = *(const f16x8*)((const char*)(LB) + R * 128 +              \
                                 ((kk * 64 + kq) ^ ((R & 7) << 4)));        \
      }                                                                     \
      _Pragma("unroll") for (int mi = 0; mi < 4; ++mi)                      \
          _Pragma("unroll") for (int ni = 0; ni < 4; ++ni)                  \
              acc[mi][ni] = __builtin_amdgcn_mfma_f32_16x16x32_f16(         \
                  af[mi], bf[ni], acc[mi][ni], 0, 0, 0);                    \
    }                                                                       \
  }

__global__ __launch_bounds__(256) void gemm2_kernel(
    const _Float16* __restrict__ Ag, const _Float16* __restrict__ Bg,
    const float* __restrict__ bias, const float* __restrict__ res,
    void* __restrict__ outp, const int* __restrict__ amask,
    int Mdim, int Ndim, int Kdim, long zsA, long zsB, long zsOut, int emode) {
  __shared__ _Float16 lA0[128 * 64];
  __shared__ _Float16 lB0[128 * 64];
  __shared__ _Float16 lA1[128 * 64];
  __shared__ _Float16 lB1[128 * 64];
  const int tid = threadIdx.x;
  const int lane = tid & 63;
  const int wid = tid >> 6;
  const int z = blockIdx.z;
  const int m0 = blockIdx.y * 128;
  const int n0 = blockIdx.x * 128;
  const _Float16* Az = Ag + (long)z * zsA + (long)m0 * Kdim;
  const _Float16* Bz = Bg + (long)z * zsB + (long)n0 * Kdim;

  const int wm = (wid >> 1) * 64;
  const int wn = (wid & 1) * 64;
  const int r16 = lane & 15;
  const int kq = (lane >> 4) * 16;  // byte offset of lane's k-quarter

  f32x4 acc[4][4];
#pragma unroll
  for (int mi = 0; mi < 4; ++mi)
#pragma unroll
    for (int ni = 0; ni < 4; ++ni) acc[mi][ni] = (f32x4){0.f, 0.f, 0.f, 0.f};

  int sr[4], sc[4];
#pragma unroll
  for (int i = 0; i < 4; ++i) {
    int o = ((i * 4 + wid) * 64 + lane) * 16;
    int r = o >> 7;
    sr[i] = r;
    sc[i] = (o & 127) ^ ((r & 7) << 4);
  }

  const int nt = Kdim >> 6;
  STAGE_TILE(lA0, lB0, 0)
  __syncthreads();
  int t = 0;
  for (; t + 2 < nt; t += 2) {
    STAGE_TILE(lA1, lB1, (t + 1) << 6)
    COMPUTE_TILE(lA0, lB0)
    __syncthreads();
    STAGE_TILE(lA0, lB0, (t + 2) << 6)
    COMPUTE_TILE(lA1, lB1)
    __syncthreads();
  }
  if (nt - t == 2) {
    STAGE_TILE(lA1, lB1, (t + 1) << 6)
    COMPUTE_TILE(lA0, lB0)
    __syncthreads();
    COMPUTE_TILE(lA1, lB1)
  } else {
    COMPUTE_TILE(lA0, lB0)
  }

  float* outF = (float*)outp + (long)z * zsOut;
  _Float16* outH = (_Float16*)outp + (long)z * zsOut;
  const int rj = (lane >> 4) << 2;
  const long MSZq = (long)BB * SS * DD;
#pragma unroll
  for (int mi = 0; mi < 4; ++mi) {
#pragma unroll
    for (int ni = 0; ni < 4; ++ni) {
      const int col = n0 + wn + ni * 16 + r16;
#pragma unroll
      for (int j = 0; j < 4; ++j) {
        const int row = m0 + wm + mi * 16 + rj + j;
        float vv = acc[mi][ni][j];
        if (emode == 0) {
          if (bias) vv += bias[col];
          outF[(long)row * Ndim + col] = vv;
        } else if (emode == 1) {  // fused qkv scatter; V written transposed
          vv += bias[col];
          int wsel = col >> 10, c = col & 1023;
          int b_ = row >> 9, s_ = row & 511;
          int hh = c >> 7, hd_ = c & 127;
          if (wsel < 2) {
            outH[wsel * MSZq + (((long)(b_ * HH + hh)) * SS + s_) * HDD + hd_] =
                (_Float16)vv;
          } else {  // V -> [B*H][HD][S]
            outH[2 * MSZq + (((long)(b_ * HH + hh)) * HDD + hd_) * SS + s_] =
                (_Float16)vv;
          }
        } else if (emode == 2) {  // scores: scale + key-pad mask, f16
          int b_ = z >> 3;
          vv = (amask[b_ * SS + col] == 0) ? -10000.0f : vv * SCALEF;
          outH[(long)row * Ndim + col] = (_Float16)vv;
        } else if (emode == 3) {  // pv scatter -> x [B,S,D] f16
          int b_ = z >> 3, hh = z & 7;
          outH[((long)(b_ * SS + row)) * DD + hh * HDD + col] = (_Float16)vv;
        } else if (emode == 4) {  // residual + bias, f32
          vv += bias[col] + res[(long)row * Ndim + col];
          outF[(long)row * Ndim + col] = vv;
        } else {  // 5: exact GELU(bias+acc), f16
          vv += bias[col];
          vv = 0.5f * vv * (1.0f + erff(vv * 0.70710678118654752f));
          outH[(long)row * Ndim + col] = (_Float16)vv;
        }
      }
    }
  }
}

// ---------------------------------------------------------------------------
__global__ __launch_bounds__(256) void embed_kernel(
    const int* __restrict__ ids, const int* __restrict__ curpos,
    const float* __restrict__ tok, const float* __restrict__ pos,
    float* __restrict__ h) {
  const int rs = blockIdx.x;
  const int s_ = rs & (SS - 1);
  const int t = ids[rs];
  const int p = curpos[0] + s_;
  const int c = threadIdx.x << 2;
  const float4 tv = *reinterpret_cast<const float4*>(&tok[(long)t * DD + c]);
  const float4 pv = *reinterpret_cast<const float4*>(&pos[(long)p * DD + c]);
  float4 o = {tv.x + pv.x, tv.y + pv.y, tv.z + pv.z, tv.w + pv.w};
  *reinterpret_cast<float4*>(&h[(long)rs * DD + c]) = o;
}

// LN: f32 in -> f16 out
__global__ __launch_bounds__(256) void ln_kernel(const float* __restrict__ in,
                                                 const float* __restrict__ g,
                                                 const float* __restrict__ bb,
                                                 _Float16* __restrict__ out) {
  const int row = blockIdx.x;
  const int c = threadIdx.x << 2;
  const float4 xv = *reinterpret_cast<const float4*>(&in[(long)row * DD + c]);
  float s = xv.x + xv.y + xv.z + xv.w;
  float ss = xv.x * xv.x + xv.y * xv.y + xv.z * xv.z + xv.w * xv.w;
#pragma unroll
  for (int off = 32; off; off >>= 1) {
    s += __shfl_down(s, off);
    ss += __shfl_down(ss, off);
  }
  __shared__ float red[8];
  const int wid = threadIdx.x >> 6, lane = threadIdx.x & 63;
  if (lane == 0) {
    red[wid] = s;
    red[4 + wid] = ss;
  }
  __syncthreads();
  if (threadIdx.x == 0) {
    s = red[0] + red[1] + red[2] + red[3];
    ss = red[4] + red[5] + red[6] + red[7];
    float mean = s * (1.0f / DD);
    float var = ss * (1.0f / DD) - mean * mean;
    red[0] = mean;
    red[1] = rsqrtf(var + EPSF);
  }
  __syncthreads();
  const float mean = red[0], rstd = red[1];
  const float4 gv = *reinterpret_cast<const float4*>(&g[c]);
  const float4 bv = *reinterpret_cast<const float4*>(&bb[c]);
  f16x4 o;
  o[0] = (_Float16)((xv.x - mean) * rstd * gv.x + bv.x);
  o[1] = (_Float16)((xv.y - mean) * rstd * gv.y + bv.y);
  o[2] = (_Float16)((xv.z - mean) * rstd * gv.z + bv.z);
  o[3] = (_Float16)((xv.w - mean) * rstd * gv.w + bv.w);
  *reinterpret_cast<f16x4*>(&out[(long)row * DD + c]) = o;
}

// wave-per-row softmax over 512 f16 cols, in place
__global__ __launch_bounds__(256) void softmax_kernel(_Float16* __restrict__ p) {
  const long row = (long)blockIdx.x * 4 + (threadIdx.x >> 6);
  const int lane = threadIdx.x & 63;
  _Float16* pr = p + row * SS;
  f16x8 hv = *reinterpret_cast<const f16x8*>(&pr[lane * 8]);
  float v[8];
#pragma unroll
  for (int j = 0; j < 8; ++j) v[j] = (float)hv[j];
  float m = v[0];
#pragma unroll
  for (int j = 1; j < 8; ++j) m = fmaxf(m, v[j]);
#pragma unroll
  for (int off = 1; off < 64; off <<= 1) m = fmaxf(m, __shfl_xor(m, off));
  float sum = 0.f;
#pragma unroll
  for (int j = 0; j < 8; ++j) {
    v[j] = expf(v[j] - m);
    sum += v[j];
  }
#pragma unroll
  for (int off = 1; off < 64; off <<= 1) sum += __shfl_xor(sum, off);
  const float inv = 1.0f / sum;
#pragma unroll
  for (int j = 0; j < 8; ++j) hv[j] = (_Float16)(v[j] * inv);
  *reinterpret_cast<f16x8*>(&pr[lane * 8]) = hv;
}

// W [K][N] f32 -> WT [N][K] f16  (64x64 tiles via LDS)
__global__ __launch_bounds__(256) void wtrans_kernel(
    const float* __restrict__ W, _Float16* __restrict__ WT, int K, int N) {
  __shared__ float t[64][65];
  const int n0 = blockIdx.x * 64, k0 = blockIdx.y * 64;
  const int tx = threadIdx.x & 63;
  const int ty = threadIdx.x >> 6;
#pragma unroll
  for (int i = 0; i < 16; ++i)
    t[i * 4 + ty][tx] = W[(long)(k0 + i * 4 + ty) * N + n0 + tx];
  __syncthreads();
#pragma unroll
  for (int i = 0; i < 16; ++i) {
    const int r = i * 4 + ty;
    WT[(long)(n0 + r) * K + k0 + tx] = (_Float16)t[tx][r];
  }
}

// pack per-layer qkv biases: bqkv[l][3072]
__global__ __launch_bounds__(256) void packb_kernel(
    const float* __restrict__ bq, const float* __restrict__ bk,
    const float* __restrict__ bv, float* __restrict__ bqkv) {
  const int i = blockIdx.x * 256 + threadIdx.x;
  const int l = i / (3 * DD), j = i % (3 * DD);
  float v;
  if (j < DD) v = bq[l * DD + j];
  else if (j < 2 * DD) v = bk[l * DD + j - DD];
  else v = bv[l * DD + j - 2 * DD];
  bqkv[i] = v;
}

// ---------------------------------------------------------------------------
extern "C" void kernel_launch(void* const* d_in, const int* in_sizes, int n_in,
                              void* d_out, int out_size, void* d_ws,
                              size_t ws_size, hipStream_t stream) {
  const int* ids = (const int*)d_in[0];
  const int* amask = (const int*)d_in[1];
  const int* curp = (const int*)d_in[2];
  const float* tok = (const float*)d_in[3];
  const float* pose = (const float*)d_in[4];
  const float* ln1s = (const float*)d_in[5];
  const float* ln1b = (const float*)d_in[6];
  const float* Wq = (const float*)d_in[7];
  const float* bq = (const float*)d_in[8];
  const float* Wk = (const float*)d_in[9];
  const float* bk = (const float*)d_in[10];
  const float* Wv = (const float*)d_in[11];
  const float* bv = (const float*)d_in[12];
  const float* Wo = (const float*)d_in[13];
  const float* bo = (const float*)d_in[14];
  const float* ln2s = (const float*)d_in[15];
  const float* ln2b = (const float*)d_in[16];
  const float* W1 = (const float*)d_in[17];
  const float* b1 = (const float*)d_in[18];
  const float* W2 = (const float*)d_in[19];
  const float* b2 = (const float*)d_in[20];
  const float* lnfs = (const float*)d_in[21];
  const float* lnfb = (const float*)d_in[22];
  const float* Wout = (const float*)d_in[23];
  const float* bout = (const float*)d_in[24];

  const long MSZ = (long)BB * SS * DD;  // 4M elements
  char* wsp = (char*)d_ws;
  float* h = (float*)wsp;                              // 16MB f32
  _Float16* x = (_Float16*)(wsp + 16u * 1024 * 1024);  // 8MB
  _Float16* q = x + MSZ;    // 8MB  (q, k, vT contiguous: qkv scatter target)
  _Float16* kb = q + MSZ;   // 8MB
  _Float16* vt = kb + MSZ;  // 8MB  [B*H][HD][S]
  _Float16* big = vt + MSZ; // 32MB (scores/probs, MLP mid)
  _Float16* wqkvT = big + (long)BB * HH * SS * SS;  // 6MB [3072][1024]
  _Float16* woT = wqkvT + 3L * DD * DD;             // 2MB
  _Float16* w1T = woT + (long)DD * DD;              // 8MB
  _Float16* w2T = w1T + (long)DD * FFF;             // 8MB
  float* bqkv = (float*)(w2T + (long)FFF * DD);     // 72KB

  const int M = BB * SS;  // 4096
  dim3 blk(256);

  embed_kernel<<<M, blk, 0, stream>>>(ids, curp, tok, pose, h);
  packb_kernel<<<(LL * 3 * DD) / 256, blk, 0, stream>>>(bq, bk, bv, bqkv);

  const dim3 gQKV(3 * DD / 128, M / 128, 1);   // (24,32)
  const dim3 gP(DD / 128, M / 128, 1);         // (8,32)
  const dim3 gS(SS / 128, SS / 128, BB * HH);  // (4,4,64)
  const dim3 gV(HDD / 128, SS / 128, BB * HH); // (1,4,64)
  const dim3 gF1(FFF / 128, M / 128, 1);       // (32,32)
  const dim3 gWt(DD / 64, DD / 64);
  const dim3 gW1t(FFF / 64, DD / 64);
  const dim3 gW2t(DD / 64, FFF / 64);

  for (int l = 0; l < LL; ++l) {
    wtrans_kernel<<<gWt, blk, 0, stream>>>(Wq + (long)l * DD * DD, wqkvT, DD, DD);
    wtrans_kernel<<<gWt, blk, 0, stream>>>(Wk + (long)l * DD * DD,
                                           wqkvT + (long)DD * DD, DD, DD);
    wtrans_kernel<<<gWt, blk, 0, stream>>>(Wv + (long)l * DD * DD,
                                           wqkvT + 2L * DD * DD, DD, DD);
    wtrans_kernel<<<gWt, blk, 0, stream>>>(Wo + (long)l * DD * DD, woT, DD, DD);
    wtrans_kernel<<<gW1t, blk, 0, stream>>>(W1 + (long)l * DD * FFF, w1T, DD, FFF);
    wtrans_kernel<<<gW2t, blk, 0, stream>>>(W2 + (long)l * FFF * DD, w2T, FFF, DD);

    ln_kernel<<<M, blk, 0, stream>>>(h, ln1s + l * DD, ln1b + l * DD, x);
    gemm2_kernel<<<gQKV, blk, 0, stream>>>(x, wqkvT, bqkv + l * 3 * DD, nullptr,
                                           q, nullptr, M, 3 * DD, DD, 0, 0, 0, 1);
    gemm2_kernel<<<gS, blk, 0, stream>>>(q, kb, nullptr, nullptr, big, amask,
                                         SS, SS, HDD, (long)SS * HDD,
                                         (long)SS * HDD, (long)SS * SS, 2);
    softmax_kernel<<<(BB * HH * SS) / 4, blk, 0, stream>>>(big);
    gemm2_kernel<<<gV, blk, 0, stream>>>(big, vt, nullptr, nullptr, x, nullptr,
                                         SS, HDD, SS, (long)SS * SS,
                                         (long)SS * HDD, 0, 3);
    gemm2_kernel<<<gP, blk, 0, stream>>>(x, woT, bo + l * DD, h, h, nullptr, M,
                                         DD, DD, 0, 0, 0, 4);
    ln_kernel<<<M, blk, 0, stream>>>(h, ln2s + l * DD, ln2b + l * DD, x);
    gemm2_kernel<<<gF1, blk, 0, stream>>>(x, w1T, b1 + l * FFF, nullptr, big,
                                          nullptr, M, FFF, DD, 0, 0, 0, 5);
    gemm2_kernel<<<gP, blk, 0, stream>>>(big, w2T, b2 + l * DD, h, h, nullptr,
                                         M, DD, FFF, 0, 0, 0, 4);
  }
  ln_kernel<<<M, blk, 0, stream>>>(h, lnfs, lnfb, x);
  wtrans_kernel<<<gWt, blk, 0, stream>>>(Wout, wqkvT, DD, DD);
  gemm2_kernel<<<gP, blk, 0, stream>>>(x, wqkvT, bout, nullptr, (float*)d_out,
                                       nullptr, M, DD, DD, 0, 0, 0, 0);
}

// Round 4
// 2059.958 us; speedup vs baseline: 2.9728x; 1.1145x over previous
//
#include <hip/hip_runtime.h>
#include <hip/hip_bf16.h>
#include <math.h>

#define BB 8
#define SS 512
#define DD 1024
#define LL 6
#define HH 8
#define HDD 128
#define FFF 4096
#define EPSF 1e-5f
#define SCALEF 0.08838834764831845f  // 1/sqrt(128)

typedef __attribute__((ext_vector_type(8))) _Float16 f16x8;
typedef __attribute__((ext_vector_type(4))) _Float16 f16x4;
typedef __attribute__((ext_vector_type(4))) float f32x4;

__device__ __forceinline__ void gload16(const void* g, void* l) {
  __builtin_amdgcn_global_load_lds(
      (const __attribute__((address_space(1))) void*)g,
      (__attribute__((address_space(3))) void*)l, 16, 0, 0);
}

// ---------------------------------------------------------------------------
// f16 GEMM: 128x64 tile, BK=64, 4 waves (wave-tile 64x32), 16x16x32 MFMA,
// global_load_lds w16, XOR-swizzle (row&7)<<4 both-sides,
// TRIPLE-buffered counted-vmcnt pipeline: per K-step
//   { s_waitcnt vmcnt(6); s_barrier; STAGE(t+2); COMPUTE(t) }
// (loads stay 2 tiles in flight across barriers; never drained to 0 in-loop).
// A [M,K] f16 row-major; B [N,K] f16 row-major.
// emode: 0 f32+bias | 1 fused-qkv scatter (N=3072, V transposed) |
//        2 f16 scores(scale+mask) | 3 f16 pv-scatter | 4 f32 residual+bias |
//        5 f16 gelu+bias
// ---------------------------------------------------------------------------
#define TSZ 24576  // slot bytes: A 16KB + B 8KB

// per-thread: 4 A-loads + 2 B-loads = 6 gload16 per stage
#define STAGE(P, K0)                                                        \
  {                                                                         \
    _Pragma("unroll") for (int i = 0; i < 4; ++i)                           \
        gload16((const char*)(Az + (long)sra[i] * Kdim + (K0)) + sca[i],    \
                (P) + i * 4096 + wid * 1024);                               \
    _Pragma("unroll") for (int i = 0; i < 2; ++i)                           \
        gload16((const char*)(Bz + (long)srb[i] * Kdim + (K0)) + scb[i],    \
                (P) + 16384 + i * 4096 + wid * 1024);                       \
  }

#define COMPUTE(P)                                                          \
  {                                                                         \
    _Pragma("unroll") for (int kk = 0; kk < 2; ++kk) {                      \
      f16x8 af[4], bf[2];                                                   \
      _Pragma("unroll") for (int mi = 0; mi < 4; ++mi) {                    \
        const int R = wm + mi * 16 + r16;                                   \
        af[mi] = *(const f16x8*)((P) + R * 128 +                            \
                                 ((kk * 64 + kq) ^ ((R & 7) << 4)));        \
      }                                                                     \
      _Pragma("unroll") for (int ni = 0; ni < 2; ++ni) {                    \
        const int R = wn + ni * 16 + r16;                                   \
        bf[ni] = *(const f16x8*)((P) + 16384 + R * 128 +                    \
                                 ((kk * 64 + kq) ^ ((R & 7) << 4)));        \
      }                                                                     \
      _Pragma("unroll") for (int mi = 0; mi < 4; ++mi)                      \
          _Pragma("unroll") for (int ni = 0; ni < 2; ++ni)                  \
              acc[mi][ni] = __builtin_amdgcn_mfma_f32_16x16x32_f16(         \
                  af[mi], bf[ni], acc[mi][ni], 0, 0, 0);                    \
    }                                                                       \
  }

#define WAITBAR6                                          \
  {                                                       \
    asm volatile("s_waitcnt vmcnt(6)" ::: "memory");      \
    __builtin_amdgcn_s_barrier();                         \
  }
#define WAITBAR0                                          \
  {                                                       \
    asm volatile("s_waitcnt vmcnt(0)" ::: "memory");      \
    __builtin_amdgcn_s_barrier();                         \
  }

__global__ __launch_bounds__(256) void gemm2_kernel(
    const _Float16* __restrict__ Ag, const _Float16* __restrict__ Bg,
    const float* __restrict__ bias, const float* __restrict__ res,
    void* __restrict__ outp, const int* __restrict__ amask,
    int Mdim, int Ndim, int Kdim, long zsA, long zsB, long zsOut, int emode) {
  __shared__ char lds[3 * TSZ];  // 72KB -> 2 blocks/CU
  const int tid = threadIdx.x;
  const int lane = tid & 63;
  const int wid = tid >> 6;
  const int z = blockIdx.z;
  const int m0 = blockIdx.y * 128;
  const int n0 = blockIdx.x * 64;
  const _Float16* Az = Ag + (long)z * zsA + (long)m0 * Kdim;
  const _Float16* Bz = Bg + (long)z * zsB + (long)n0 * Kdim;

  const int wm = (wid >> 1) * 64;  // wave-tile 64x32
  const int wn = (wid & 1) * 32;
  const int r16 = lane & 15;
  const int kq = (lane >> 4) * 16;  // byte offset of lane's k-quarter

  f32x4 acc[4][2];
#pragma unroll
  for (int mi = 0; mi < 4; ++mi)
#pragma unroll
    for (int ni = 0; ni < 2; ++ni) acc[mi][ni] = (f32x4){0.f, 0.f, 0.f, 0.f};

  // staging geometry (A: 4 chunks of 32 rows; B: 2 chunks of 32 rows)
  int sra[4], srb[2], sca[4], scb[2];
  {
    const int cb = (tid * 16) & 127;  // column-byte within row, const over i
#pragma unroll
    for (int i = 0; i < 4; ++i) {
      int r = i * 32 + (tid >> 3);
      sra[i] = r;
      sca[i] = cb ^ ((r & 7) << 4);
    }
#pragma unroll
    for (int i = 0; i < 2; ++i) {
      int r = i * 32 + (tid >> 3);
      srb[i] = r;
      scb[i] = cb ^ ((r & 7) << 4);
    }
  }

  const int nt = Kdim >> 6;
  char* p0 = lds;
  char* p1 = lds + TSZ;
  char* p2 = lds + 2 * TSZ;
  STAGE(p0, 0)
  STAGE(p1, 64)
  int t = 0;
  for (; t + 2 < nt; ++t) {
    WAITBAR6
    STAGE(p2, (t + 2) << 6)
    COMPUTE(p0)
    char* tmp = p0;
    p0 = p1;
    p1 = p2;
    p2 = tmp;
  }
  WAITBAR6
  COMPUTE(p0)
  WAITBAR0
  COMPUTE(p1)

  float* outF = (float*)outp + (long)z * zsOut;
  _Float16* outH = (_Float16*)outp + (long)z * zsOut;
  const int rj = (lane >> 4) << 2;
  const long MSZq = (long)BB * SS * DD;
#pragma unroll
  for (int mi = 0; mi < 4; ++mi) {
#pragma unroll
    for (int ni = 0; ni < 2; ++ni) {
      const int col = n0 + wn + ni * 16 + r16;
#pragma unroll
      for (int j = 0; j < 4; ++j) {
        const int row = m0 + wm + mi * 16 + rj + j;
        float vv = acc[mi][ni][j];
        if (emode == 0) {
          if (bias) vv += bias[col];
          outF[(long)row * Ndim + col] = vv;
        } else if (emode == 1) {  // fused qkv scatter; V written transposed
          vv += bias[col];
          int wsel = col >> 10, c = col & 1023;
          int b_ = row >> 9, s_ = row & 511;
          int hh = c >> 7, hd_ = c & 127;
          if (wsel < 2) {
            outH[wsel * MSZq + (((long)(b_ * HH + hh)) * SS + s_) * HDD + hd_] =
                (_Float16)vv;
          } else {  // V -> [B*H][HD][S]
            outH[2 * MSZq + (((long)(b_ * HH + hh)) * HDD + hd_) * SS + s_] =
                (_Float16)vv;
          }
        } else if (emode == 2) {  // scores: scale + key-pad mask, f16
          int b_ = z >> 3;
          vv = (amask[b_ * SS + col] == 0) ? -10000.0f : vv * SCALEF;
          outH[(long)row * Ndim + col] = (_Float16)vv;
        } else if (emode == 3) {  // pv scatter -> x [B,S,D] f16
          int b_ = z >> 3, hh = z & 7;
          outH[((long)(b_ * SS + row)) * DD + hh * HDD + col] = (_Float16)vv;
        } else if (emode == 4) {  // residual + bias, f32
          vv += bias[col] + res[(long)row * Ndim + col];
          outF[(long)row * Ndim + col] = vv;
        } else {  // 5: exact GELU(bias+acc), f16
          vv += bias[col];
          vv = 0.5f * vv * (1.0f + erff(vv * 0.70710678118654752f));
          outH[(long)row * Ndim + col] = (_Float16)vv;
        }
      }
    }
  }
}

// ---------------------------------------------------------------------------
__global__ __launch_bounds__(256) void embed_kernel(
    const int* __restrict__ ids, const int* __restrict__ curpos,
    const float* __restrict__ tok, const float* __restrict__ pos,
    float* __restrict__ h) {
  const int rs = blockIdx.x;
  const int s_ = rs & (SS - 1);
  const int t = ids[rs];
  const int p = curpos[0] + s_;
  const int c = threadIdx.x << 2;
  const float4 tv = *reinterpret_cast<const float4*>(&tok[(long)t * DD + c]);
  const float4 pv = *reinterpret_cast<const float4*>(&pos[(long)p * DD + c]);
  float4 o = {tv.x + pv.x, tv.y + pv.y, tv.z + pv.z, tv.w + pv.w};
  *reinterpret_cast<float4*>(&h[(long)rs * DD + c]) = o;
}

// LN: f32 in -> f16 out
__global__ __launch_bounds__(256) void ln_kernel(const float* __restrict__ in,
                                                 const float* __restrict__ g,
                                                 const float* __restrict__ bb,
                                                 _Float16* __restrict__ out) {
  const int row = blockIdx.x;
  const int c = threadIdx.x << 2;
  const float4 xv = *reinterpret_cast<const float4*>(&in[(long)row * DD + c]);
  float s = xv.x + xv.y + xv.z + xv.w;
  float ss = xv.x * xv.x + xv.y * xv.y + xv.z * xv.z + xv.w * xv.w;
#pragma unroll
  for (int off = 32; off; off >>= 1) {
    s += __shfl_down(s, off);
    ss += __shfl_down(ss, off);
  }
  __shared__ float red[8];
  const int wid = threadIdx.x >> 6, lane = threadIdx.x & 63;
  if (lane == 0) {
    red[wid] = s;
    red[4 + wid] = ss;
  }
  __syncthreads();
  if (threadIdx.x == 0) {
    s = red[0] + red[1] + red[2] + red[3];
    ss = red[4] + red[5] + red[6] + red[7];
    float mean = s * (1.0f / DD);
    float var = ss * (1.0f / DD) - mean * mean;
    red[0] = mean;
    red[1] = rsqrtf(var + EPSF);
  }
  __syncthreads();
  const float mean = red[0], rstd = red[1];
  const float4 gv = *reinterpret_cast<const float4*>(&g[c]);
  const float4 bv = *reinterpret_cast<const float4*>(&bb[c]);
  f16x4 o;
  o[0] = (_Float16)((xv.x - mean) * rstd * gv.x + bv.x);
  o[1] = (_Float16)((xv.y - mean) * rstd * gv.y + bv.y);
  o[2] = (_Float16)((xv.z - mean) * rstd * gv.z + bv.z);
  o[3] = (_Float16)((xv.w - mean) * rstd * gv.w + bv.w);
  *reinterpret_cast<f16x4*>(&out[(long)row * DD + c]) = o;
}

// wave-per-row softmax over 512 f16 cols, in place
__global__ __launch_bounds__(256) void softmax_kernel(_Float16* __restrict__ p) {
  const long row = (long)blockIdx.x * 4 + (threadIdx.x >> 6);
  const int lane = threadIdx.x & 63;
  _Float16* pr = p + row * SS;
  f16x8 hv = *reinterpret_cast<const f16x8*>(&pr[lane * 8]);
  float v[8];
#pragma unroll
  for (int j = 0; j < 8; ++j) v[j] = (float)hv[j];
  float m = v[0];
#pragma unroll
  for (int j = 1; j < 8; ++j) m = fmaxf(m, v[j]);
#pragma unroll
  for (int off = 1; off < 64; off <<= 1) m = fmaxf(m, __shfl_xor(m, off));
  float sum = 0.f;
#pragma unroll
  for (int j = 0; j < 8; ++j) {
    v[j] = expf(v[j] - m);
    sum += v[j];
  }
#pragma unroll
  for (int off = 1; off < 64; off <<= 1) sum += __shfl_xor(sum, off);
  const float inv = 1.0f / sum;
#pragma unroll
  for (int j = 0; j < 8; ++j) hv[j] = (_Float16)(v[j] * inv);
  *reinterpret_cast<f16x8*>(&pr[lane * 8]) = hv;
}

// W [K][N] f32 -> WT [N][K] f16  (64x64 tiles via LDS)
__global__ __launch_bounds__(256) void wtrans_kernel(
    const float* __restrict__ W, _Float16* __restrict__ WT, int K, int N) {
  __shared__ float t[64][65];
  const int n0 = blockIdx.x * 64, k0 = blockIdx.y * 64;
  const int tx = threadIdx.x & 63;
  const int ty = threadIdx.x >> 6;
#pragma unroll
  for (int i = 0; i < 16; ++i)
    t[i * 4 + ty][tx] = W[(long)(k0 + i * 4 + ty) * N + n0 + tx];
  __syncthreads();
#pragma unroll
  for (int i = 0; i < 16; ++i) {
    const int r = i * 4 + ty;
    WT[(long)(n0 + r) * K + k0 + tx] = (_Float16)t[tx][r];
  }
}

// pack per-layer qkv biases: bqkv[l][3072]
__global__ __launch_bounds__(256) void packb_kernel(
    const float* __restrict__ bq, const float* __restrict__ bk,
    const float* __restrict__ bv, float* __restrict__ bqkv) {
  const int i = blockIdx.x * 256 + threadIdx.x;
  const int l = i / (3 * DD), j = i % (3 * DD);
  float v;
  if (j < DD) v = bq[l * DD + j];
  else if (j < 2 * DD) v = bk[l * DD + j - DD];
  else v = bv[l * DD + j - 2 * DD];
  bqkv[i] = v;
}

// ---------------------------------------------------------------------------
extern "C" void kernel_launch(void* const* d_in, const int* in_sizes, int n_in,
                              void* d_out, int out_size, void* d_ws,
                              size_t ws_size, hipStream_t stream) {
  const int* ids = (const int*)d_in[0];
  const int* amask = (const int*)d_in[1];
  const int* curp = (const int*)d_in[2];
  const float* tok = (const float*)d_in[3];
  const float* pose = (const float*)d_in[4];
  const float* ln1s = (const float*)d_in[5];
  const float* ln1b = (const float*)d_in[6];
  const float* Wq = (const float*)d_in[7];
  const float* bq = (const float*)d_in[8];
  const float* Wk = (const float*)d_in[9];
  const float* bk = (const float*)d_in[10];
  const float* Wv = (const float*)d_in[11];
  const float* bv = (const float*)d_in[12];
  const float* Wo = (const float*)d_in[13];
  const float* bo = (const float*)d_in[14];
  const float* ln2s = (const float*)d_in[15];
  const float* ln2b = (const float*)d_in[16];
  const float* W1 = (const float*)d_in[17];
  const float* b1 = (const float*)d_in[18];
  const float* W2 = (const float*)d_in[19];
  const float* b2 = (const float*)d_in[20];
  const float* lnfs = (const float*)d_in[21];
  const float* lnfb = (const float*)d_in[22];
  const float* Wout = (const float*)d_in[23];
  const float* bout = (const float*)d_in[24];

  const long MSZ = (long)BB * SS * DD;  // 4M elements
  char* wsp = (char*)d_ws;
  float* h = (float*)wsp;                              // 16MB f32
  _Float16* x = (_Float16*)(wsp + 16u * 1024 * 1024);  // 8MB
  _Float16* q = x + MSZ;    // 8MB  (q, k, vT contiguous: qkv scatter target)
  _Float16* kb = q + MSZ;   // 8MB
  _Float16* vt = kb + MSZ;  // 8MB  [B*H][HD][S]
  _Float16* big = vt + MSZ; // 32MB (scores/probs, MLP mid)
  _Float16* wqkvT = big + (long)BB * HH * SS * SS;  // 6MB [3072][1024]
  _Float16* woT = wqkvT + 3L * DD * DD;             // 2MB
  _Float16* w1T = woT + (long)DD * DD;              // 8MB
  _Float16* w2T = w1T + (long)DD * FFF;             // 8MB
  float* bqkv = (float*)(w2T + (long)FFF * DD);     // 72KB

  const int M = BB * SS;  // 4096
  dim3 blk(256);

  embed_kernel<<<M, blk, 0, stream>>>(ids, curp, tok, pose, h);
  packb_kernel<<<(LL * 3 * DD) / 256, blk, 0, stream>>>(bq, bk, bv, bqkv);

  const dim3 gQKV(3 * DD / 64, M / 128, 1);    // (48,32)
  const dim3 gP(DD / 64, M / 128, 1);          // (16,32)
  const dim3 gS(SS / 64, SS / 128, BB * HH);   // (8,4,64)
  const dim3 gV(HDD / 64, SS / 128, BB * HH);  // (2,4,64)
  const dim3 gF1(FFF / 64, M / 128, 1);        // (64,32)
  const dim3 gWt(DD / 64, DD / 64);
  const dim3 gW1t(FFF / 64, DD / 64);
  const dim3 gW2t(DD / 64, FFF / 64);

  for (int l = 0; l < LL; ++l) {
    wtrans_kernel<<<gWt, blk, 0, stream>>>(Wq + (long)l * DD * DD, wqkvT, DD, DD);
    wtrans_kernel<<<gWt, blk, 0, stream>>>(Wk + (long)l * DD * DD,
                                           wqkvT + (long)DD * DD, DD, DD);
    wtrans_kernel<<<gWt, blk, 0, stream>>>(Wv + (long)l * DD * DD,
                                           wqkvT + 2L * DD * DD, DD, DD);
    wtrans_kernel<<<gWt, blk, 0, stream>>>(Wo + (long)l * DD * DD, woT, DD, DD);
    wtrans_kernel<<<gW1t, blk, 0, stream>>>(W1 + (long)l * DD * FFF, w1T, DD, FFF);
    wtrans_kernel<<<gW2t, blk, 0, stream>>>(W2 + (long)l * FFF * DD, w2T, FFF, DD);

    ln_kernel<<<M, blk, 0, stream>>>(h, ln1s + l * DD, ln1b + l * DD, x);
    gemm2_kernel<<<gQKV, blk, 0, stream>>>(x, wqkvT, bqkv + l * 3 * DD, nullptr,
                                           q, nullptr, M, 3 * DD, DD, 0, 0, 0, 1);
    gemm2_kernel<<<gS, blk, 0, stream>>>(q, kb, nullptr, nullptr, big, amask,
                                         SS, SS, HDD, (long)SS * HDD,
                                         (long)SS * HDD, (long)SS * SS, 2);
    softmax_kernel<<<(BB * HH * SS) / 4, blk, 0, stream>>>(big);
    gemm2_kernel<<<gV, blk, 0, stream>>>(big, vt, nullptr, nullptr, x, nullptr,
                                         SS, HDD, SS, (long)SS * SS,
                                         (long)SS * HDD, 0, 3);
    gemm2_kernel<<<gP, blk, 0, stream>>>(x, woT, bo + l * DD, h, h, nullptr, M,
                                         DD, DD, 0, 0, 0, 4);
    ln_kernel<<<M, blk, 0, stream>>>(h, ln2s + l * DD, ln2b + l * DD, x);
    gemm2_kernel<<<gF1, blk, 0, stream>>>(x, w1T, b1 + l * FFF, nullptr, big,
                                          nullptr, M, FFF, DD, 0, 0, 0, 5);
    gemm2_kernel<<<gP, blk, 0, stream>>>(big, w2T, b2 + l * DD, h, h, nullptr,
                                         M, DD, FFF, 0, 0, 0, 4);
  }
  ln_kernel<<<M, blk, 0, stream>>>(h, lnfs, lnfb, x);
  wtrans_kernel<<<gWt, blk, 0, stream>>>(Wout, wqkvT, DD, DD);
  gemm2_kernel<<<gP, blk, 0, stream>>>(x, wqkvT, bout, nullptr, (float*)d_out,
                                       nullptr, M, DD, DD, 0, 0, 0, 0);
}